// Round 1
// baseline (4229.640 us; speedup 1.0000x reference)
//
#include <hip/hip_runtime.h>

#define NV 16384
#define EH 16256
#define EVV 16256
#define ED 16129
#define NE 48641
#define NT 32258
#define ND 32259
#define OUTERF 32258

typedef unsigned int u32;
typedef unsigned short u16;

// ---------------- ws layout ----------------
static __host__ __device__ constexpr size_t al256(size_t x) { return (x + 255) & ~(size_t)255; }
static constexpr size_t OFF_ACC   = 0;
static constexpr size_t OFF_R32   = 256;
static constexpr size_t OFF_FRK   = OFF_R32   + al256(NV * 4);
static constexpr size_t OFF_FVAL  = OFF_FRK   + al256(ND * 4);
static constexpr size_t OFF_FRV   = OFF_FVAL  + al256(ND * 4);
static constexpr size_t OFF_DVAL  = OFF_FRV   + al256(ND * 4);
static constexpr size_t OFF_EPP   = OFF_DVAL  + al256(NE * 4);
static constexpr size_t OFF_EPD   = OFF_EPP   + al256(NE * 4);
static constexpr size_t OFF_LPA   = OFF_EPD   + al256(NE * 4);
static constexpr size_t OFF_LPB   = OFF_LPA   + al256(NE * 8);
static constexpr size_t OFF_LDA   = OFF_LPB   + al256(NE * 8);
static constexpr size_t OFF_LDB   = OFF_LDA   + al256(NE * 8);
static constexpr size_t OFF_TKEY  = OFF_LDB   + al256(NE * 8);
static constexpr size_t OFF_TAB   = OFF_TKEY  + al256(NT * 4);
static constexpr size_t OFF_TDV   = OFF_TAB   + al256(NT * 4);
static constexpr size_t OFF_CNT   = OFF_TDV   + al256(NT * 4);
static constexpr size_t OFF_SAB   = OFF_CNT   + al256(NV * 4);
static constexpr size_t OFF_SDV   = OFF_SAB   + al256(NT * 4);
static constexpr size_t OFF_CANDP = OFF_SDV   + al256(NT * 4);
static constexpr size_t OFF_CANDD = OFF_CANDP + al256(NV * 4);

__device__ __forceinline__ u32 fmap(float x) {
  u32 u = __float_as_uint(x);
  return (u & 0x80000000u) ? ~u : (u | 0x80000000u);
}
__device__ __forceinline__ float funmap(u32 m) {
  u32 u = (m & 0x80000000u) ? (m & 0x7FFFFFFFu) : ~m;
  return __uint_as_float(u);
}

__device__ __forceinline__ int findh(volatile u16* par, int x) {
  while (true) {
    int p = par[x];
    if (p == x) return x;
    int gp = par[p];
    if (gp == p) return p;
    par[x] = (u16)gp;
    x = gp;
  }
}

// ---------------- K0: init ----------------
__global__ void k_init(float* accF, u32* accU, u32* r32, u32* frk, u32* cnt) {
  int i = blockIdx.x * 256 + threadIdx.x;
  if (i == 0) { accF[0] = 0.f; accF[1] = 0.f; accU[2] = 0u; }
  if (i < NV) { r32[i] = 0u; cnt[i] = 0u; }
  if (i < ND) frk[i] = 0u;
}

// ---------------- K1: face values + vertex reductions ----------------
__global__ void k_build(const float* __restrict__ beta, float* fval, float* accF, u32* accU) {
  __shared__ float ls[4], lm[4];
  int bid = blockIdx.x, tid = threadIdx.x;
  if (bid < 64) {
    int v = (bid << 8) + tid;
    float b = beta[v];
    float s = b, m = b;
    for (int off = 32; off >= 1; off >>= 1) {
      s += __shfl_down(s, off);
      m = fmaxf(m, __shfl_down(m, off));
    }
    int wid = tid >> 6;
    if ((tid & 63) == 0) { ls[wid] = s; lm[wid] = m; }
    __syncthreads();
    if (tid == 0) {
      s = ls[0] + ls[1] + ls[2] + ls[3];
      m = fmaxf(fmaxf(lm[0], lm[1]), fmaxf(lm[2], lm[3]));
      atomicAdd(&accF[1], s);
      atomicMax(&accU[2], fmap(m));
    }
  } else {
    int t = ((bid - 64) << 8) + tid;
    if (t < NT) {
      int i, j, v0; float fv;
      if (t < ED) { i = t / 127; j = t - i * 127; v0 = (i << 7) + j;
        fv = fminf(fminf(beta[v0], beta[v0 + 128]), beta[v0 + 129]); }  // L(i,j)
      else { int u = t - ED; i = u / 127; j = u - i * 127; v0 = (i << 7) + j;
        fv = fminf(fminf(beta[v0], beta[v0 + 1]), beta[v0 + 129]); }    // U(i,j)
      fval[t] = -fv;
      if (t == 0) fval[OUTERF] = __builtin_inff();
    }
  }
}

// ---------------- K2v: vertex ranks (ascending beta, id tiebreak) ----------------
__global__ void k_rankv(const float* __restrict__ beta, u32* r32) {
  int v = blockIdx.x * 256 + threadIdx.x;
  int c = blockIdx.y;
  float bv = beta[v];
  int u0 = c << 10;
  int cnt = 0;
#pragma unroll 8
  for (int u = u0; u < u0 + 1024; ++u) {
    float bu = beta[u];
    cnt += (bu < bv || (bu == bv && u < v)) ? 1 : 0;
  }
  if (cnt) atomicAdd(&r32[v], (u32)cnt);
}

// ---------------- K2f: face ranks (descending fval, id tiebreak) ----------------
__global__ void k_rankf(const float* __restrict__ fval, u32* frk) {
  int g = blockIdx.x * 256 + threadIdx.x;
  if (g >= ND) return;
  float fg = fval[g];
  int u0 = blockIdx.y * 4033;
  int u1 = min(u0 + 4033, ND);
  int cnt = 0;
#pragma unroll 8
  for (int u = u0; u < u1; ++u) {
    float fu = fval[u];
    cnt += (fu > fg || (fu == fg && u < g)) ? 1 : 0;
  }
  if (cnt) atomicAdd(&frk[g], (u32)cnt);
}

// ---------------- K2b: scatter rank->value table ----------------
__global__ void k_scatf(const float* __restrict__ fval, const u32* __restrict__ frk, float* frv) {
  int g = blockIdx.x * 256 + threadIdx.x;
  if (g < ND) frv[frk[g]] = fval[g];
}

// ---------------- K3: build edges ----------------
__global__ void k_edges(const float* __restrict__ beta, const u32* __restrict__ r32,
                        float* dvals, u32* epP, u32* epD, uint2* listP, uint2* listD) {
  int e = blockIdx.x * 256 + threadIdx.x;
  if (e >= NE) return;
  int eu, ev, fa, fb;
  if (e < EH) {                        // horizontal (i,j)-(i,j+1)
    int i = e / 127, j = e - (e / 127) * 127;
    eu = (i << 7) + j; ev = eu + 1;
    fa = (i < 127) ? (ED + i * 127 + j) : OUTERF;   // U(i,j)
    fb = (i >= 1) ? ((i - 1) * 127 + j) : OUTERF;   // L(i-1,j)
  } else if (e < EH + EVV) {           // vertical (i,j)-(i+1,j)
    int k = e - EH;
    int i = k >> 7, j = k & 127;
    eu = (i << 7) + j; ev = eu + 128;
    fa = (j < 127) ? (i * 127 + j) : OUTERF;        // L(i,j)
    fb = (j >= 1) ? (ED + i * 127 + (j - 1)) : OUTERF; // U(i,j-1)
  } else {                             // diagonal (i,j)-(i+1,j+1)
    int k = e - EH - EVV;
    int i = k / 127, j = k - (k / 127) * 127;
    eu = (i << 7) + j; ev = eu + 129;
    fa = i * 127 + j; fb = ED + i * 127 + j;
  }
  float bu = beta[eu], bv = beta[ev];
  float dv = -fminf(bu, bv);                 // f-space edge value
  int cv = (bu <= bv) ? eu : ev;             // critical vertex (min beta)
  u32 rr = r32[cv];                          // rank: small beta -> small rank = large f
  dvals[e] = dv;
  u32 pp = (u32)eu | ((u32)ev << 16);
  u32 dd = (u32)fa | ((u32)fb << 16);
  epP[e] = pp;
  epD[e] = dd;
  listP[e] = make_uint2(((16383u - rr) << 17) | (u32)e, pp); // primal: ascending f
  listD[e] = make_uint2((rr << 17) | (u32)e, dd);            // dual: descending f
}

// ---------------- K4: Boruvka (block 0 = primal MST weight, block 1 = dual maxST edges) ----------------
__global__ __launch_bounds__(1024) void k_boruvka(
    const float* __restrict__ dvals, const u32* __restrict__ epP, const u32* __restrict__ epD,
    uint2* lPA, uint2* lPB, uint2* lDA, uint2* lDB,
    u32* candP, u32* candD,
    u32* treeKey, u32* treeAB, float* treeDV, float* accF) {
  const bool dual = (blockIdx.x != 0);
  const int Nn = dual ? ND : NV;
  const u32* ep = dual ? epD : epP;
  u32* cand = dual ? candD : candP;
  uint2* listA = dual ? lDA : lPA;
  uint2* listB = dual ? lDB : lPB;
  __shared__ u16 par[ND];
  __shared__ int nCur, nNxt, treeCnt, changed;
  __shared__ float wred[16];
  int tid = threadIdx.x;
  for (int v = tid; v < Nn; v += 1024) { par[v] = (u16)v; cand[v] = 0xFFFFFFFFu; }
  if (tid == 0) { nCur = NE; treeCnt = 0; }
  float wloc = 0.f;
  __syncthreads();
  for (int round = 0; round < 40; ++round) {
    uint2* cur = (round & 1) ? listB : listA;
    uint2* nxt = (round & 1) ? listA : listB;
    if (tid == 0) nNxt = 0;
    __syncthreads();
    int n = nCur;
    for (int i = tid; i < n; i += 1024) {
      uint2 rec = cur[i];
      int a = (int)(rec.y & 0xFFFFu), b = (int)(rec.y >> 16);
      int ra = findh((volatile u16*)par, a);
      int rb = findh((volatile u16*)par, b);
      if (ra != rb) {
        int pos = atomicAdd(&nNxt, 1);
        nxt[pos] = make_uint2(rec.x, (u32)ra | ((u32)rb << 16));
        atomicMin(&cand[ra], rec.x);
        atomicMin(&cand[rb], rec.x);
      }
    }
    __syncthreads();
    u32 hooks[32];
#pragma unroll
    for (int it = 0; it < 32; ++it) {
      hooks[it] = 0xFFFFFFFFu;
      int v = tid + (it << 10);
      if (v < Nn) {
        u32 c = ((volatile u32*)cand)[v];
        if (c != 0xFFFFFFFFu && par[v] == (u16)v) {
          int eid = (int)(c & 0x1FFFFu);
          u32 ab = ep[eid];
          int ea = (int)(ab & 0xFFFFu), eb = (int)(ab >> 16);
          int ra = findh((volatile u16*)par, ea);
          int rb = findh((volatile u16*)par, eb);
          int w = (ra == v) ? rb : ra;
          u32 cw = ((volatile u32*)cand)[w];
          bool mutual = (cw != 0xFFFFFFFFu) && ((int)(cw & 0x1FFFFu) == eid);
          if (!mutual || v < w) {
            hooks[it] = (u32)w;
            if (dual) {
              int pos = atomicAdd(&treeCnt, 1);
              treeKey[pos] = c; treeAB[pos] = ab; treeDV[pos] = dvals[eid];
            } else {
              atomicAdd(&treeCnt, 1);
              wloc += dvals[eid];
            }
          }
        }
      }
    }
    __syncthreads();
#pragma unroll
    for (int it = 0; it < 32; ++it) {
      int v = tid + (it << 10);
      if (v < Nn && hooks[it] != 0xFFFFFFFFu) par[v] = (u16)hooks[it];
    }
    __syncthreads();
    for (int jr = 0; jr < 24; ++jr) {
      if (tid == 0) changed = 0;
      __syncthreads();
      for (int v = tid; v < Nn; v += 1024) {
        int p = par[v]; int pp = par[p];
        if (p != pp) { par[v] = (u16)pp; changed = 1; }
      }
      __syncthreads();
      if (!changed) break;
    }
    __syncthreads();
    if (tid == 0) nCur = nNxt;
    __syncthreads();
    if (treeCnt >= Nn - 1 || nCur == 0) break;
    for (int v = tid; v < Nn; v += 1024) cand[v] = 0xFFFFFFFFu;
    __syncthreads();
  }
  for (int off = 32; off >= 1; off >>= 1) wloc += __shfl_down(wloc, off);
  if ((tid & 63) == 0) wred[tid >> 6] = wloc;
  __syncthreads();
  if (tid == 0) {
    float s = 0.f;
    for (int w = 0; w < 16; ++w) s += wred[w];
    atomicAdd(&accF[0], s);
  }
}

// ---------------- K5: counting-sort dual tree edges by rank bucket ----------------
__global__ __launch_bounds__(1024) void k_sorttree(
    const u32* __restrict__ treeKey, const u32* __restrict__ treeAB, const float* __restrict__ treeDV,
    u32* sAB, float* sDV, u32* gtmp) {
  __shared__ u32 cnt[NV];  // 64 KB
  int tid = threadIdx.x;
  for (int b = tid; b < NV; b += 1024) cnt[b] = 0u;
  __syncthreads();
  for (int t = tid; t < NT; t += 1024) atomicAdd(&cnt[treeKey[t] >> 17], 1u);
  __syncthreads();
  u32 loc[16]; u32 s = 0;
#pragma unroll
  for (int k = 0; k < 16; ++k) { loc[k] = s; s += cnt[(tid << 4) + k]; }
  int lane = tid & 63, wid = tid >> 6;
  u32 incl = s;
  for (int off = 1; off < 64; off <<= 1) {
    u32 o = __shfl_up(incl, off);
    if (lane >= off) incl += o;
  }
  if (lane == 63) gtmp[wid] = incl;
  __syncthreads();
  u32 wbase = 0;
  for (int w = 0; w < 16; ++w) { u32 tt = gtmp[w]; wbase += (w < wid) ? tt : 0u; }
  u32 base = wbase + incl - s;
#pragma unroll
  for (int k = 0; k < 16; ++k) cnt[(tid << 4) + k] = base + loc[k];
  __syncthreads();
  for (int t = tid; t < NT; t += 1024) {
    u32 key = treeKey[t];
    u32 pos = atomicAdd(&cnt[key >> 17], 1u);
    sAB[pos] = treeAB[t];
    sDV[pos] = treeDV[t];
  }
}

// ---------------- K6: exact Kruskal pairing on sorted dual tree (1 wave, speculative chunks) ----------------
__global__ __launch_bounds__(64) void k_pair(
    const u32* __restrict__ sAB, const float* __restrict__ sDV,
    const u32* __restrict__ frk, const float* __restrict__ frv,
    const float* __restrict__ accF, const u32* __restrict__ accU, float* out) {
  __shared__ u16 par[ND];
  int lane = threadIdx.x;
  for (int v = lane; v < ND; v += 64) par[v] = (u16)v;
  __syncthreads();
  float sum1 = 0.f, max1 = 0.f;
  const int nch = (NT + 63) >> 6;
  for (int ch = 0; ch < nch; ++ch) {
    int idx = (ch << 6) + lane;
    bool act = idx < NT;
    u32 pa = 0xFFFFFFFFu, pb = 0xFFFFFFFFu;
    float dv = 0.f;
    if (act) {
      u32 ab = sAB[idx];
      dv = sDV[idx];
      int ra = findh((volatile u16*)par, (int)(ab & 0xFFFFu));
      int rb = findh((volatile u16*)par, (int)(ab >> 16));
      pa = ((u32)ra << 16) | frk[ra];   // birth rank of root r is invariantly frk[r]
      pb = ((u32)rb << 16) | frk[rb];
    }
    u32 myS = 0, myC = 0;
    bool did = false;
    for (int i = 0; i < 64; ++i) {
      u32 A = (u32)__builtin_amdgcn_readlane((int)pa, i);
      u32 B = (u32)__builtin_amdgcn_readlane((int)pb, i);
      if ((A >> 16) != (B >> 16)) {
        bool aold = (A & 0xFFFFu) < (B & 0xFFFFu);   // smaller rank = older (larger fval)
        u32 S = aold ? A : B;
        u32 C = aold ? B : A;
        if (lane == i) { myS = S; myC = C; did = true; }
        if ((pa >> 16) == (C >> 16)) pa = S;
        if ((pb >> 16) == (C >> 16)) pb = S;
      }
    }
    if (did) {
      par[myC >> 16] = (u16)(myS >> 16);
      float bar = frv[myC & 0xFFFFu] - dv;   // fval(younger birth) - dval(edge) >= 0
      sum1 += bar;
      max1 = fmaxf(max1, bar);
    }
    __syncthreads();
  }
  for (int off = 32; off >= 1; off >>= 1) {
    sum1 += __shfl_down(sum1, off);
    max1 = fmaxf(max1, __shfl_down(max1, off));
  }
  if (lane == 0) {
    float loss0 = accF[0] + accF[1] - funmap(accU[2]);  // W_MST(f) + sum(beta) - max(beta)
    float loss1 = sum1 - max1;                           // PartialSumBarcodeLengths(dim1, skip=1)
    out[0] = loss0 + loss1;
  }
}

extern "C" void kernel_launch(void* const* d_in, const int* in_sizes, int n_in,
                              void* d_out, int out_size, void* d_ws, size_t ws_size,
                              hipStream_t stream) {
  const float* beta = (const float*)d_in[0];
  float* out = (float*)d_out;
  char* ws = (char*)d_ws;
  float* accF = (float*)(ws + OFF_ACC);
  u32*   accU = (u32*)(ws + OFF_ACC);
  u32*   gtmp = (u32*)(ws + OFF_ACC + 64);
  u32* r32 = (u32*)(ws + OFF_R32);
  u32* frk = (u32*)(ws + OFF_FRK);
  float* fval = (float*)(ws + OFF_FVAL);
  float* frv = (float*)(ws + OFF_FRV);
  float* dvals = (float*)(ws + OFF_DVAL);
  u32* epP = (u32*)(ws + OFF_EPP);
  u32* epD = (u32*)(ws + OFF_EPD);
  uint2* lPA = (uint2*)(ws + OFF_LPA);
  uint2* lPB = (uint2*)(ws + OFF_LPB);
  uint2* lDA = (uint2*)(ws + OFF_LDA);
  uint2* lDB = (uint2*)(ws + OFF_LDB);
  u32* treeKey = (u32*)(ws + OFF_TKEY);
  u32* treeAB = (u32*)(ws + OFF_TAB);
  float* treeDV = (float*)(ws + OFF_TDV);
  u32* cnt = (u32*)(ws + OFF_CNT);
  u32* sAB = (u32*)(ws + OFF_SAB);
  float* sDV = (float*)(ws + OFF_SDV);
  u32* candP = (u32*)(ws + OFF_CANDP);
  u32* candD = (u32*)(ws + OFF_CANDD);

  hipLaunchKernelGGL(k_init, dim3(127), dim3(256), 0, stream, accF, accU, r32, frk, cnt);
  hipLaunchKernelGGL(k_build, dim3(191), dim3(256), 0, stream, beta, fval, accF, accU);
  hipLaunchKernelGGL(k_rankv, dim3(64, 16), dim3(256), 0, stream, beta, r32);
  hipLaunchKernelGGL(k_rankf, dim3(127, 8), dim3(256), 0, stream, fval, frk);
  hipLaunchKernelGGL(k_scatf, dim3(127), dim3(256), 0, stream, fval, frk, frv);
  hipLaunchKernelGGL(k_edges, dim3(191), dim3(256), 0, stream, beta, r32, dvals, epP, epD, lPA, lDA);
  hipLaunchKernelGGL(k_boruvka, dim3(2), dim3(1024), 0, stream, dvals, epP, epD,
                     lPA, lPB, lDA, lDB, candP, candD, treeKey, treeAB, treeDV, accF);
  hipLaunchKernelGGL(k_sorttree, dim3(1), dim3(1024), 0, stream, treeKey, treeAB, treeDV, sAB, sDV, gtmp);
  hipLaunchKernelGGL(k_pair, dim3(1), dim3(64), 0, stream, sAB, sDV, frk, frv, accF, accU, out);
}